// Round 1
// 65.258 us; speedup vs baseline: 1.0469x; 1.0469x over previous
//
#include <hip/hip_runtime.h>
#include <math.h>

#define BB 128
#define NN 512
#define CHUNKS 8
#define RPB 64                 // rows per block, one per lane
#define NWAVES 8               // 512 threads/block
#define NT (NWAVES * 64)
#define JPW (NN / NWAVES)      // 64-column slab per wave
#define GRID (BB * CHUNKS)
#define EPSF 1e-7f
#define ONEP (1.0f + EPSF)
#define TWOEPS (2.0f * EPSF)

// One block = (batch b, 64-row chunk). 512 threads = 8 waves.
// LANE-PER-ROW layout: lane l owns row chunk*64+l entirely; wave w covers
// column slab j in [w*64, (w+1)*64). No per-row cross-lane reduction at all:
//   pass1: em_j = (T_j >= T_i) ? e_j : 0 cached in 64 regs (static idx,
//          fully unrolled), partial S accumulated; S combined across the
//          8 waves through LDS (one barrier) -- replaces the old 6-deep
//          ds_swizzle butterfly per row.
//   pass2: partial product of q = max(ONEP - em*invS, 2eps) over the cached
//          slab (fma+max+mul only, no LDS re-read, no recompare).
//   Diagonal fold (identical to previous kernel): wave0 multiplies its
//   partial by F = e_i * invS / q_ii, so -sum_w log(P_w) = part1 + part2.
//   Dead rows (not eliminated) branch-free: Ti := +INF -> em == 0, Sc := 1
//   keeps rcp/log finite, contribution * elim(=0).
// Partials WRITTEN to distinct ws slots (no memset/atomics/fences; device
// fences force L2 writeback of the 256MiB poisoned ws):
//   ws[0..GRID)        block partial sums (scaled by batch_valid)
//   ws[GRID..GRID+BB)  per-batch valid flag (chunk==0 block)
__global__ __launch_bounds__(NT) void cox_main(const float* __restrict__ pred,
                                               const float* __restrict__ target,
                                               const int* __restrict__ valid,
                                               float* __restrict__ ws) {
    __shared__ __align__(16) float s_e[NN];    // exp(pred)
    __shared__ __align__(16) float s_tm[NN];   // masked target
    __shared__ float s_mx[NWAVES];
    __shared__ float s_ct[NWAVES];
    __shared__ float s_S[NWAVES][RPB];         // per-slab partial S
    __shared__ float s_L[NWAVES][RPB];         // per-slab log(partial prod)

    const int b     = blockIdx.x / CHUNKS;
    const int chunk = blockIdx.x % CHUNKS;
    const int tid   = threadIdx.x;
    const int lane  = tid & 63;
    const int wave  = tid >> 6;

    // ---- stage inputs (one element per thread), batch max + valid count ----
    {
        float p = pred[b * NN + tid];
        float t = target[b * NN + tid];
        int   v = valid[b * NN + tid];
        float tm = v ? t : -1.0f;
        s_e[tid]  = __expf(p);
        s_tm[tid] = tm;
        float lmax = tm;
        float lcnt = v ? 1.0f : 0.0f;
        #pragma unroll
        for (int off = 32; off; off >>= 1) {
            lmax = fmaxf(lmax, __shfl_xor(lmax, off, 64));
            lcnt += __shfl_xor(lcnt, off, 64);
        }
        if (lane == 0) { s_mx[wave] = lmax; s_ct[wave] = lcnt; }
    }
    __syncthreads();

    float bmax = s_mx[0], bcnt = s_ct[0];
    #pragma unroll
    for (int w = 1; w < NWAVES; ++w) {
        bmax = fmaxf(bmax, s_mx[w]);
        bcnt += s_ct[w];
    }
    const float batch_valid = (bcnt >= 2.0f) ? 1.0f : 0.0f;

    // ---- per-lane row state ----
    const int   row    = chunk * RPB + lane;
    const float ti_raw = s_tm[row];
    const float ei     = s_e[row];
    const bool  el     = (ti_raw > 0.0f) && (ti_raw < bmax);
    const float elim   = el ? 1.0f : 0.0f;
    const float Ti     = el ? ti_raw : INFINITY;   // dead row: em all-zero

    // ---- pass 1: em cache + partial S over this wave's 64-column slab ----
    const int jb = wave * JPW;
    float em[JPW];                  // fully unrolled -> stays in VGPRs
    float S0 = 0.0f, S1 = 0.0f, S2 = 0.0f, S3 = 0.0f;
    #pragma unroll
    for (int k = 0; k < JPW; k += 4) {
        const float4 t4 = *(const float4*)&s_tm[jb + k];   // wave-uniform bcast
        const float4 e4 = *(const float4*)&s_e[jb + k];
        em[k + 0] = (t4.x >= Ti) ? e4.x : 0.0f; S0 += em[k + 0];
        em[k + 1] = (t4.y >= Ti) ? e4.y : 0.0f; S1 += em[k + 1];
        em[k + 2] = (t4.z >= Ti) ? e4.z : 0.0f; S2 += em[k + 2];
        em[k + 3] = (t4.w >= Ti) ? e4.w : 0.0f; S3 += em[k + 3];
    }
    s_S[wave][lane] = (S0 + S1) + (S2 + S3);
    __syncthreads();

    float S = s_S[0][lane];
    #pragma unroll
    for (int w = 1; w < NWAVES; ++w) S += s_S[w][lane];
    const float Sc   = el ? S : 1.0f;              // dead row: finite
    const float invS = __builtin_amdgcn_rcpf(Sc);

    // ---- pass 2: partial product of q over the cached slab ----
    float P0 = 1.0f, P1 = 1.0f, P2 = 1.0f, P3 = 1.0f;
    #pragma unroll
    for (int k = 0; k < JPW; k += 4) {
        P0 *= fmaxf(fmaf(-em[k + 0], invS, ONEP), TWOEPS);
        P1 *= fmaxf(fmaf(-em[k + 1], invS, ONEP), TWOEPS);
        P2 *= fmaxf(fmaf(-em[k + 2], invS, ONEP), TWOEPS);
        P3 *= fmaxf(fmaf(-em[k + 3], invS, ONEP), TWOEPS);
    }
    float P = (P0 * P1) * (P2 * P3);
    if (wave == 0) {
        // diagonal fold: removes q_ii, adds part1 (log S - p_i)
        const float qii = fmaxf(fmaf(-ei, invS, ONEP), TWOEPS);
        P *= ei * invS * __builtin_amdgcn_rcpf(qii);
    }
    s_L[wave][lane] = __logf(P);
    __syncthreads();

    // ---- wave 0: combine slab logs per row, reduce 64 rows, write ----
    if (wave == 0) {
        float lsum = s_L[0][lane];
        #pragma unroll
        for (int w = 1; w < NWAVES; ++w) lsum += s_L[w][lane];
        float acc = -elim * lsum;
        #pragma unroll
        for (int off = 32; off; off >>= 1) acc += __shfl_xor(acc, off, 64);
        if (lane == 0) {
            ws[blockIdx.x] = acc * batch_valid;
            if (chunk == 0) ws[GRID + b] = batch_valid;
        }
    }
}

// Single 256-thread block: sum GRID partials and BB valid flags, divide.
__global__ __launch_bounds__(256) void cox_final(const float* __restrict__ ws,
                                                 float* __restrict__ out) {
    __shared__ float s_tot[4];
    __shared__ float s_cnt[4];
    const int tid  = threadIdx.x;
    const int lane = tid & 63;
    const int wave = tid >> 6;

    float tot = 0.0f;
    #pragma unroll
    for (int k = 0; k < GRID / 256; ++k) tot += ws[tid + 256 * k];
    float cnt = (tid < BB) ? ws[GRID + tid] : 0.0f;

    #pragma unroll
    for (int off = 32; off; off >>= 1) {
        tot += __shfl_xor(tot, off, 64);
        cnt += __shfl_xor(cnt, off, 64);
    }
    if (lane == 0) { s_tot[wave] = tot; s_cnt[wave] = cnt; }
    __syncthreads();
    if (tid == 0) {
        float T = s_tot[0] + s_tot[1] + s_tot[2] + s_tot[3];
        float C = s_cnt[0] + s_cnt[1] + s_cnt[2] + s_cnt[3];
        out[0] = T / fmaxf(C, 1.0f);
    }
}

extern "C" void kernel_launch(void* const* d_in, const int* in_sizes, int n_in,
                              void* d_out, int out_size, void* d_ws, size_t ws_size,
                              hipStream_t stream) {
    const float* pred   = (const float*)d_in[0];
    const float* target = (const float*)d_in[1];
    const int*   valid  = (const int*)d_in[2];
    float* out = (float*)d_out;
    float* ws  = (float*)d_ws;

    cox_main<<<GRID, NT, 0, stream>>>(pred, target, valid, ws);
    cox_final<<<1, 256, 0, stream>>>(ws, out);
}